// Round 4
// baseline (347.449 us; speedup 1.0000x reference)
//
#include <hip/hip_runtime.h>
#include <hip/hip_bf16.h>

typedef unsigned int uint;
typedef unsigned short u16;

#define NGR 512
#define EDG 1048576      // total symmetrized edge count (row array length)
#define KC1 896          // 7*128
#define KC2 1792         // 7*256

__device__ __forceinline__ float bf2f(u16 h) { return __uint_as_float(((uint)h) << 16); }
__device__ __forceinline__ u16 f2bf(float f) {
  uint u = __float_as_uint(f);
  uint r = (u + 0x7fffu + ((u >> 16) & 1u)) >> 16;
  return (u16)r;
}

typedef __attribute__((ext_vector_type(8))) short bf16x8;
typedef __attribute__((ext_vector_type(4))) float f32x4;

// ---------------- weight transposes f32 -> bf16 (B^T layout for TN GEMM) ----------------
__global__ void k_tr_w1(const float* __restrict__ W1, u16* __restrict__ Wt1) {
  int kf = blockIdx.x, c = threadIdx.x;            // 896 blocks x 256 thr
  Wt1[(size_t)c * KC1 + kf] = f2bf(W1[(size_t)kf * 256 + c]);
}
__global__ void k_tr_w23(const float* __restrict__ W2, const float* __restrict__ W3, u16* __restrict__ Wt23) {
  int kf = blockIdx.x, c = threadIdx.x;            // 1792 blocks x 128 thr
  float v = (c < 64) ? W2[(size_t)kf * 64 + c] : W3[(size_t)kf * 64 + (c - 64)];
  Wt23[(size_t)c * KC2 + kf] = f2bf(v);
}
__global__ void k_tr_wf1(const float* __restrict__ Wf1, u16* __restrict__ Wf1t) {
  int kf = blockIdx.x, c = threadIdx.x;            // 64 blocks x 256 thr
  Wf1t[(size_t)c * 64 + kf] = f2bf(Wf1[(size_t)kf * 256 + c]);
}
__global__ void k_tr_wf2(const float* __restrict__ Wf2, u16* __restrict__ Wf2t) {
  int n = blockIdx.x, k = threadIdx.x;             // 2048 blocks x 256 thr (pad N to 2048)
  Wf2t[(size_t)n * 256 + k] = (n < 2016) ? f2bf(Wf2[(size_t)k * 2016 + n]) : (u16)0;
}

// ---------------- fused stage 1: per-graph A-build + Cheb recurrence + h1 = relu(sum_k T_k@W1[k] + b1) ----------------
__global__ __launch_bounds__(256) void k_stage1(const int* __restrict__ ei, const float* __restrict__ x,
                                                const u16* __restrict__ Wt1, const float* __restrict__ b1,
                                                u16* __restrict__ h1) {
  int g = blockIdx.x, t = threadIdx.x;
  int lane = t & 63, w = t >> 6;
  __shared__ float sA[64 * 66];                  // 16896 B (f32 Lhat, padded)
  __shared__ int ideg[64];
  __shared__ float sdis[64];
  __shared__ __align__(16) u16 cur[64 * 136];    // 17408 B (current T_k, bf16)
  // ---- build A ----
  for (int e = t; e < 64 * 66; e += 256) sA[e] = 0.f;
  if (t < 64) ideg[t] = 0;
  __syncthreads();
  int s[4], d[4];
  #pragma unroll
  for (int u = 0; u < 4; ++u) {
    int idx = g * 1024 + t + u * 256;
    s[u] = ei[idx] & 63;                          // graph-blocked numbering -> local id
    d[u] = ei[EDG + idx] & 63;
    atomicAdd(&ideg[s[u]], 1);
    atomicAdd(&ideg[d[u]], 1);
  }
  __syncthreads();
  if (t < 64) sdis[t] = rsqrtf((float)ideg[t]);   // deg >= 16 always
  __syncthreads();
  #pragma unroll
  for (int u = 0; u < 4; ++u) {
    float wg = -sdis[s[u]] * sdis[d[u]];
    atomicAdd(&sA[s[u] * 66 + d[u]], wg);
    atomicAdd(&sA[d[u] * 66 + s[u]], wg);
  }
  // ---- T0 = x -> cur (bf16) ----
  const float4* xg = (const float4*)(x + (size_t)g * 8192);
  for (int p = t; p < 2048; p += 256) {
    int r = p >> 5, c4 = (p & 31) * 4;
    float4 v = xg[p];
    uint2 pk; u16* ps = (u16*)&pk;
    ps[0] = f2bf(v.x); ps[1] = f2bf(v.y); ps[2] = f2bf(v.z); ps[3] = f2bf(v.w);
    *(uint2*)&cur[r * 136 + c4] = pk;
  }
  __syncthreads();
  int i = t >> 2, f0 = (t & 3) * 32;             // recurrence ownership: row i, cols [f0, f0+32)
  uint4 prv[4];                                   // T_{k-2}[own] (packed bf16)
  f32x4 acc[4][4];                                // wave w: out cols [w*64, w*64+64)
  #pragma unroll
  for (int m = 0; m < 4; ++m)
    #pragma unroll
    for (int n = 0; n < 4; ++n) acc[m][n] = (f32x4){0.f, 0.f, 0.f, 0.f};

  for (int k = 0; k < 7; ++k) {
    if (k > 0) {
      // y = A @ cur (vector f32)
      float y[32];
      #pragma unroll
      for (int e = 0; e < 32; ++e) y[e] = 0.f;
      for (int j = 0; j < 64; ++j) {
        float a = sA[i * 66 + j];
        #pragma unroll
        for (int u = 0; u < 4; ++u) {
          uint4 v = *(const uint4*)&cur[j * 136 + f0 + u * 8];
          const u16* pv = (const u16*)&v;
          #pragma unroll
          for (int e = 0; e < 8; ++e) y[u * 8 + e] += a * bf2f(pv[e]);
        }
      }
      uint4 pn[4];
      #pragma unroll
      for (int u = 0; u < 4; ++u) pn[u] = *(const uint4*)&cur[i * 136 + f0 + u * 8];
      __syncthreads();                            // all reads of cur done
      if (k >= 2) {
        #pragma unroll
        for (int u = 0; u < 4; ++u) {
          const u16* pv = (const u16*)&prv[u];
          #pragma unroll
          for (int e = 0; e < 8; ++e) y[u * 8 + e] = 2.f * y[u * 8 + e] - bf2f(pv[e]);
        }
      }
      #pragma unroll
      for (int u = 0; u < 4; ++u) {
        uint4 pk; u16* ps = (u16*)&pk;
        #pragma unroll
        for (int e = 0; e < 8; ++e) ps[e] = f2bf(y[u * 8 + e]);
        *(uint4*)&cur[i * 136 + f0 + u * 8] = pk;
        prv[u] = pn[u];
      }
      __syncthreads();                            // writes visible
    }
    // acc += T_k @ W1[k]   (MFMA; B-frags straight from L2-resident Wt1)
    #pragma unroll
    for (int ks = 0; ks < 4; ++ks) {
      bf16x8 af[4];
      #pragma unroll
      for (int m = 0; m < 4; ++m)
        af[m] = *(const bf16x8*)&cur[(m * 16 + (lane & 15)) * 136 + ks * 32 + (lane >> 4) * 8];
      #pragma unroll
      for (int nj = 0; nj < 4; ++nj) {
        int n = w * 64 + nj * 16 + (lane & 15);
        bf16x8 bfr = *(const bf16x8*)(Wt1 + (size_t)n * KC1 + k * 128 + ks * 32 + (lane >> 4) * 8);
        #pragma unroll
        for (int m = 0; m < 4; ++m)
          acc[m][nj] = __builtin_amdgcn_mfma_f32_16x16x32_bf16(af[m], bfr, acc[m][nj], 0, 0, 0);
      }
    }
  }
  // epilogue: bias + relu -> h1 bf16   (C/D: col=lane&15, row=(lane>>4)*4+r)
  #pragma unroll
  for (int nj = 0; nj < 4; ++nj) {
    int gcol = w * 64 + nj * 16 + (lane & 15);
    float bias = b1[gcol];
    #pragma unroll
    for (int m = 0; m < 4; ++m) {
      int row0 = m * 16 + (lane >> 4) * 4;
      #pragma unroll
      for (int r = 0; r < 4; ++r) {
        float v = acc[m][nj][r] + bias;
        v = v > 0.f ? v : 0.f;
        h1[(size_t)(g * 64 + row0 + r) * 256 + gcol] = f2bf(v);
      }
    }
  }
}

// ---------------- fused stage 2: A-build + recurrence + out2-acc in regs + pool + reparameterize ----------------
__global__ __launch_bounds__(256) void k_stage2(const int* __restrict__ ei, const u16* __restrict__ h1,
                                                const u16* __restrict__ Wt23, const float* __restrict__ b2,
                                                const float* __restrict__ b3, const float* __restrict__ eps,
                                                float* __restrict__ dout, u16* __restrict__ zb) {
  int g = blockIdx.x, t = threadIdx.x;
  int lane = t & 63, w = t >> 6;
  __shared__ float sA[64 * 66];                  // 16896 B
  __shared__ int ideg[64];
  __shared__ float sdis[64];
  __shared__ __align__(16) u16 cur[64 * 264];    // 33792 B (current T_k over h1, bf16)
  __shared__ float smu[128];
  // ---- build A ----
  for (int e = t; e < 64 * 66; e += 256) sA[e] = 0.f;
  if (t < 64) ideg[t] = 0;
  __syncthreads();
  int s[4], d[4];
  #pragma unroll
  for (int u = 0; u < 4; ++u) {
    int idx = g * 1024 + t + u * 256;
    s[u] = ei[idx] & 63;
    d[u] = ei[EDG + idx] & 63;
    atomicAdd(&ideg[s[u]], 1);
    atomicAdd(&ideg[d[u]], 1);
  }
  __syncthreads();
  if (t < 64) sdis[t] = rsqrtf((float)ideg[t]);
  __syncthreads();
  #pragma unroll
  for (int u = 0; u < 4; ++u) {
    float wg = -sdis[s[u]] * sdis[d[u]];
    atomicAdd(&sA[s[u] * 66 + d[u]], wg);
    atomicAdd(&sA[d[u] * 66 + s[u]], wg);
  }
  // ---- T0 = h1 -> cur ----
  const uint4* hg = (const uint4*)(h1 + (size_t)g * 16384);
  for (int p = t; p < 2048; p += 256) {
    int r = p >> 5, c8 = (p & 31) * 8;
    *(uint4*)&cur[r * 264 + c8] = hg[p];
  }
  __syncthreads();
  int i = t >> 2, f0 = (t & 3) * 64;             // recurrence ownership: row i, cols [f0, f0+64)
  uint4 prv[8];
  f32x4 acc[4][2];                                // wave w: out cols [w*32, w*32+32)
  #pragma unroll
  for (int m = 0; m < 4; ++m)
    #pragma unroll
    for (int n = 0; n < 2; ++n) acc[m][n] = (f32x4){0.f, 0.f, 0.f, 0.f};

  for (int k = 0; k < 7; ++k) {
    if (k > 0) {
      float y[64];
      #pragma unroll
      for (int e = 0; e < 64; ++e) y[e] = 0.f;
      for (int j = 0; j < 64; ++j) {
        float a = sA[i * 66 + j];
        #pragma unroll
        for (int u = 0; u < 8; ++u) {
          uint4 v = *(const uint4*)&cur[j * 264 + f0 + u * 8];
          const u16* pv = (const u16*)&v;
          #pragma unroll
          for (int e = 0; e < 8; ++e) y[u * 8 + e] += a * bf2f(pv[e]);
        }
      }
      uint4 pn[8];
      #pragma unroll
      for (int u = 0; u < 8; ++u) pn[u] = *(const uint4*)&cur[i * 264 + f0 + u * 8];
      __syncthreads();
      if (k >= 2) {
        #pragma unroll
        for (int u = 0; u < 8; ++u) {
          const u16* pv = (const u16*)&prv[u];
          #pragma unroll
          for (int e = 0; e < 8; ++e) y[u * 8 + e] = 2.f * y[u * 8 + e] - bf2f(pv[e]);
        }
      }
      #pragma unroll
      for (int u = 0; u < 8; ++u) {
        uint4 pk; u16* ps = (u16*)&pk;
        #pragma unroll
        for (int e = 0; e < 8; ++e) ps[e] = f2bf(y[u * 8 + e]);
        *(uint4*)&cur[i * 264 + f0 + u * 8] = pk;
        prv[u] = pn[u];
      }
      __syncthreads();
    }
    // acc += T_k @ [W2[k] | W3[k]]
    #pragma unroll
    for (int ks = 0; ks < 8; ++ks) {
      bf16x8 af[4];
      #pragma unroll
      for (int m = 0; m < 4; ++m)
        af[m] = *(const bf16x8*)&cur[(m * 16 + (lane & 15)) * 264 + ks * 32 + (lane >> 4) * 8];
      #pragma unroll
      for (int nj = 0; nj < 2; ++nj) {
        int n = w * 32 + nj * 16 + (lane & 15);
        bf16x8 bfr = *(const bf16x8*)(Wt23 + (size_t)n * KC2 + k * 256 + ks * 32 + (lane >> 4) * 8);
        #pragma unroll
        for (int m = 0; m < 4; ++m)
          acc[m][nj] = __builtin_amdgcn_mfma_f32_16x16x32_bf16(af[m], bfr, acc[m][nj], 0, 0, 0);
      }
    }
  }
  // ---- pool over the 64 rows (all rows live in this block's acc) ----
  float cs[2];
  #pragma unroll
  for (int nj = 0; nj < 2; ++nj) {
    float ssum = 0.f;
    #pragma unroll
    for (int m = 0; m < 4; ++m)
      #pragma unroll
      for (int r = 0; r < 4; ++r) ssum += acc[m][nj][r];
    ssum += __shfl_xor(ssum, 16);
    ssum += __shfl_xor(ssum, 32);
    cs[nj] = ssum;
  }
  if (lane < 16) {
    smu[w * 32 + lane] = cs[0];
    smu[w * 32 + 16 + lane] = cs[1];
  }
  __syncthreads();
  if (t < 64) {
    float m = smu[t] * (1.f / 64.f) + b2[t];
    float l = smu[64 + t] * (1.f / 64.f) + b3[t];
    float z = m + eps[g * 64 + t] * expf(0.5f * l);
    dout[1032192 + g * 64 + t] = m;
    dout[1032192 + 32768 + g * 64 + t] = l;
    zb[g * 64 + t] = f2bf(z);
  }
}

// ---------------- MFMA TN GEMM (head): C[M][ldc] = A[M][lda] * Bt[N][ldb]^T ----------------
// EPI 0: bias+relu -> bf16 ; 3: bias+sigmoid -> f32, guard N<2016
template <int EPI>
__global__ __launch_bounds__(256) void k_gemm_tn(const u16* __restrict__ A, int lda,
                                                 const u16* __restrict__ Bt, int ldb, int K,
                                                 const float* __restrict__ bias_a,
                                                 u16* __restrict__ Cbf, float* __restrict__ Cf32, int ldc) {
  __shared__ __align__(16) u16 As[2][128 * 40];
  __shared__ __align__(16) u16 Bs[2][128 * 40];
  int t = threadIdx.x;
  int lane = t & 63, wave = t >> 6;
  int wr = wave >> 1, wc = wave & 1;
  int bm = blockIdx.x * 128, bn = blockIdx.y * 128;
  int ra = t >> 1, ka = (t & 1) * 16;
  const u16* Ap = A + (size_t)(bm + ra) * lda + ka;
  const u16* Bp = Bt + (size_t)(bn + ra) * ldb + ka;

  f32x4 acc[4][4];
  #pragma unroll
  for (int m = 0; m < 4; ++m)
    #pragma unroll
    for (int n = 0; n < 4; ++n) acc[m][n] = (f32x4){0.f, 0.f, 0.f, 0.f};

  int nk = K >> 5;
  {
    uint4 a0 = *(const uint4*)(Ap), a1 = *(const uint4*)(Ap + 8);
    uint4 b0 = *(const uint4*)(Bp), b1 = *(const uint4*)(Bp + 8);
    *(uint4*)&As[0][ra * 40 + ka] = a0; *(uint4*)&As[0][ra * 40 + ka + 8] = a1;
    *(uint4*)&Bs[0][ra * 40 + ka] = b0; *(uint4*)&Bs[0][ra * 40 + ka + 8] = b1;
  }
  for (int ks = 0; ks < nk; ++ks) {
    int cu = ks & 1;
    uint4 na0, na1, nb0, nb1;
    bool pf = (ks + 1 < nk);
    if (pf) {
      int k0 = (ks + 1) << 5;
      na0 = *(const uint4*)(Ap + k0); na1 = *(const uint4*)(Ap + k0 + 8);
      nb0 = *(const uint4*)(Bp + k0); nb1 = *(const uint4*)(Bp + k0 + 8);
    }
    __syncthreads();
    bf16x8 af[4], bfr[4];
    #pragma unroll
    for (int m = 0; m < 4; ++m)
      af[m] = *(const bf16x8*)&As[cu][(wr * 64 + m * 16 + (lane & 15)) * 40 + (lane >> 4) * 8];
    #pragma unroll
    for (int n = 0; n < 4; ++n)
      bfr[n] = *(const bf16x8*)&Bs[cu][(wc * 64 + n * 16 + (lane & 15)) * 40 + (lane >> 4) * 8];
    #pragma unroll
    for (int m = 0; m < 4; ++m)
      #pragma unroll
      for (int n = 0; n < 4; ++n)
        acc[m][n] = __builtin_amdgcn_mfma_f32_16x16x32_bf16(af[m], bfr[n], acc[m][n], 0, 0, 0);
    if (pf) {
      int nb = (ks + 1) & 1;
      __syncthreads();
      *(uint4*)&As[nb][ra * 40 + ka] = na0; *(uint4*)&As[nb][ra * 40 + ka + 8] = na1;
      *(uint4*)&Bs[nb][ra * 40 + ka] = nb0; *(uint4*)&Bs[nb][ra * 40 + ka + 8] = nb1;
    }
  }
  #pragma unroll
  for (int n = 0; n < 4; ++n) {
    int gcol = bn + wc * 64 + n * 16 + (lane & 15);
    float bias = (EPI == 3) ? ((gcol < 2016) ? bias_a[gcol] : 0.f) : bias_a[gcol];
    #pragma unroll
    for (int m = 0; m < 4; ++m) {
      int grow0 = bm + wr * 64 + m * 16 + (lane >> 4) * 4;
      #pragma unroll
      for (int r = 0; r < 4; ++r) {
        float v = acc[m][n][r];
        size_t off = (size_t)(grow0 + r) * ldc + gcol;
        if (EPI == 0) { v += bias; v = v > 0.f ? v : 0.f; Cbf[off] = f2bf(v); }
        else { if (gcol < 2016) { v += bias; Cf32[off] = 1.f / (1.f + expf(-v)); } }
      }
    }
  }
}

// ---------------- host launch ----------------
extern "C" void kernel_launch(void* const* d_in, const int* in_sizes, int n_in,
                              void* d_out, int out_size, void* d_ws, size_t ws_size,
                              hipStream_t stream) {
  const float* x   = (const float*)d_in[0];
  const int*   ei  = (const int*)d_in[1];
  const float* eps = (const float*)d_in[3];
  const float* W1  = (const float*)d_in[4];  const float* b1  = (const float*)d_in[5];
  const float* W2  = (const float*)d_in[6];  const float* b2  = (const float*)d_in[7];
  const float* W3  = (const float*)d_in[8];  const float* b3  = (const float*)d_in[9];
  const float* Wf1 = (const float*)d_in[10]; const float* bf1 = (const float*)d_in[11];
  const float* Wf2 = (const float*)d_in[12]; const float* bf2v= (const float*)d_in[13];
  float* dout = (float*)d_out;
  char* ws = (char*)d_ws;

  // workspace: 19,103,744 bytes total (small: avoid any chance of overflowing ws_size)
  u16* Wt1  = (u16*)(ws + 0);                      //   458,752  [256][896]
  u16* Wt23 = (u16*)(ws + 458752);                 //   458,752  [128][1792]
  u16* Wf1t = (u16*)(ws + 917504);                 //    32,768  [256][64]
  u16* Wf2t = (u16*)(ws + 950272);                 // 1,048,576  [2048][256]
  u16* zb   = (u16*)(ws + 1998848);                //    65,536  [512][64]
  u16* hh   = (u16*)(ws + 2064384);                //   262,144  [512][256]
  u16* h1   = (u16*)(ws + 2326528);                // 16,777,216 [32768][256]

  k_tr_w1  <<<dim3(896),  dim3(256), 0, stream>>>(W1, Wt1);
  k_tr_w23 <<<dim3(1792), dim3(128), 0, stream>>>(W2, W3, Wt23);
  k_tr_wf1 <<<dim3(64),   dim3(256), 0, stream>>>(Wf1, Wf1t);
  k_tr_wf2 <<<dim3(2048), dim3(256), 0, stream>>>(Wf2, Wf2t);
  k_stage1 <<<dim3(NGR),  dim3(256), 0, stream>>>(ei, x, Wt1, b1, h1);
  k_stage2 <<<dim3(NGR),  dim3(256), 0, stream>>>(ei, h1, Wt23, b2, b3, eps, dout, zb);
  k_gemm_tn<0><<<dim3(4, 2),  dim3(256), 0, stream>>>(zb, 64, Wf1t, 64, 64, bf1, hh, nullptr, 256);
  k_gemm_tn<3><<<dim3(4, 16), dim3(256), 0, stream>>>(hh, 256, Wf2t, 256, 256, bf2v, nullptr, dout, 2016);
}

// Round 6
// 126.313 us; speedup vs baseline: 2.7507x; 2.7507x over previous
//
#include <hip/hip_runtime.h>

typedef unsigned int uint;
typedef unsigned short u16;
typedef _Float16 f16;
typedef __attribute__((ext_vector_type(8))) _Float16 f16x8;
typedef __attribute__((ext_vector_type(4))) float f32x4;

#define NGR 512
#define EDG 1048576      // total symmetrized edge count
#define KC1 896          // 7*128
#define KC2 1792         // 7*256

union uhcv { u16 u; f16 h; };
__device__ __forceinline__ u16 f2h(float f) { uhcv x; x.h = (f16)f; return x.u; }
__device__ __forceinline__ float h2f(u16 v) { uhcv x; x.u = v; return (float)x.h; }

// ---------------- merged weight transposes f32 -> f16 ----------------
__global__ __launch_bounds__(256) void k_prep(const float* __restrict__ W1, const float* __restrict__ W2,
                                              const float* __restrict__ W3, const float* __restrict__ Wf1,
                                              const float* __restrict__ Wf2,
                                              u16* __restrict__ Wt1, u16* __restrict__ Wt23,
                                              u16* __restrict__ Wf1t, u16* __restrict__ Wf2t) {
  int b = blockIdx.x, t = threadIdx.x;
  if (b < 896) {                       // Wt1[n][kf] = W1[kf][n]
    int kf = b;
    Wt1[(size_t)t * KC1 + kf] = f2h(W1[(size_t)kf * 256 + t]);
  } else if (b < 1792) {               // Wt23[c][kf] = [W2|W3][kf][c]
    int idx = (b - 896) * 256 + t;
    int kf = idx >> 7, c = idx & 127;
    float v = (c < 64) ? W2[(size_t)kf * 64 + c] : W3[(size_t)kf * 64 + (c - 64)];
    Wt23[(size_t)c * KC2 + kf] = f2h(v);
  } else if (b < 1856) {               // Wf1t[c][kf] = Wf1[kf][c]
    int idx = (b - 1792) * 256 + t;
    int c = idx >> 6, kf = idx & 63;
    Wf1t[(size_t)c * 64 + kf] = f2h(Wf1[(size_t)kf * 256 + c]);
  } else {                             // Wf2t[n][k] = Wf2[k][n], pad n to 2048
    int idx = (b - 1856) * 256 + t;
    int n = idx >> 8, k = idx & 255;
    Wf2t[(size_t)n * 256 + k] = (n < 2016) ? f2h(Wf2[(size_t)k * 2016 + n]) : (u16)0;
  }
}

// ======== fused stage 1: A-build + MFMA Cheb recurrence + h1 = relu(sum_k T_k@W1[k] + b1) ========
// LDS map (bytes): Ah[64][72]u16 @0 (9216) | cur[64][136]u16 @9216 (17408) | curT[128][72]u16 @26624 (18432)
//                  sAf f32[64][66] aliases @26624 | ideg @45056 | sdis @45312 | total 45568
__global__ __launch_bounds__(256, 2) void k_stage1(const int* __restrict__ ei, const float* __restrict__ x,
                                                   const u16* __restrict__ Wt1, const float* __restrict__ b1,
                                                   u16* __restrict__ h1) {
  extern __shared__ char sm1[];
  u16* Ah     = (u16*)(sm1 + 0);
  u16* cur    = (u16*)(sm1 + 9216);
  u16* curT   = (u16*)(sm1 + 26624);
  float* sAf  = (float*)(sm1 + 26624);
  int* ideg   = (int*)(sm1 + 45056);
  float* sdis = (float*)(sm1 + 45312);
  int g = blockIdx.x, t = threadIdx.x;
  int lane = t & 63, w = t >> 6, l15 = lane & 15, G = lane >> 4;
  // ---- build Lhat (f32) ----
  for (int e = t; e < 64 * 66; e += 256) sAf[e] = 0.f;
  if (t < 64) ideg[t] = 0;
  __syncthreads();
  int sl[4], dl[4];
  #pragma unroll
  for (int u = 0; u < 4; ++u) {
    int idx = g * 1024 + t + u * 256;
    sl[u] = ei[idx] & 63; dl[u] = ei[EDG + idx] & 63;
    atomicAdd(&ideg[sl[u]], 1); atomicAdd(&ideg[dl[u]], 1);
  }
  __syncthreads();
  if (t < 64) sdis[t] = rsqrtf((float)ideg[t]);
  __syncthreads();
  #pragma unroll
  for (int u = 0; u < 4; ++u) {
    float wg = -sdis[sl[u]] * sdis[dl[u]];
    atomicAdd(&sAf[sl[u] * 66 + dl[u]], wg);
    atomicAdd(&sAf[dl[u] * 66 + sl[u]], wg);
  }
  __syncthreads();
  for (int e = t; e < 4096; e += 256) Ah[(e >> 6) * 72 + (e & 63)] = f2h(sAf[(e >> 6) * 66 + (e & 63)]);
  __syncthreads();           // sAf reads done before curT (same bytes) is written
  // ---- T0 = x -> cur + curT ----
  const float4* xg = (const float4*)(x + (size_t)g * 8192);
  #pragma unroll
  for (int p0 = 0; p0 < 8; ++p0) {
    int p = t + p0 * 256;
    int r = p >> 5, c4 = (p & 31) * 4;
    float4 v = xg[p];
    u16 e0 = f2h(v.x), e1 = f2h(v.y), e2 = f2h(v.z), e3 = f2h(v.w);
    uint2 pk; u16* ps = (u16*)&pk; ps[0] = e0; ps[1] = e1; ps[2] = e2; ps[3] = e3;
    *(uint2*)&cur[r * 136 + c4] = pk;
    curT[(c4 + 0) * 72 + r] = e0; curT[(c4 + 1) * 72 + r] = e1;
    curT[(c4 + 2) * 72 + r] = e2; curT[(c4 + 3) * 72 + r] = e3;
  }
  __syncthreads();
  f32x4 acc_o[4][4];
  #pragma unroll
  for (int m = 0; m < 4; ++m)
    #pragma unroll
    for (int n = 0; n < 4; ++n) acc_o[m][n] = (f32x4){0.f, 0.f, 0.f, 0.f};
  uint2 pm2[4][2];
  #pragma unroll
  for (int m = 0; m < 4; ++m)
    #pragma unroll
    for (int n = 0; n < 2; ++n) pm2[m][n] = (uint2){0u, 0u};

  for (int k = 0; k < 7; ++k) {
    if (k > 0) {
      // Y = Lhat @ T_{k-1}: A-op = Ah[i][j], B-op = curT[f][j]
      f32x4 acc_y[4][2];
      #pragma unroll
      for (int m = 0; m < 4; ++m)
        #pragma unroll
        for (int n = 0; n < 2; ++n) acc_y[m][n] = (f32x4){0.f, 0.f, 0.f, 0.f};
      #pragma unroll
      for (int ks = 0; ks < 2; ++ks) {
        f16x8 bq[2];
        #pragma unroll
        for (int nt = 0; nt < 2; ++nt)
          bq[nt] = *(const f16x8*)&curT[(w * 32 + nt * 16 + l15) * 72 + ks * 32 + G * 8];
        #pragma unroll
        for (int mt = 0; mt < 4; ++mt) {
          f16x8 a = *(const f16x8*)&Ah[(mt * 16 + l15) * 72 + ks * 32 + G * 8];
          #pragma unroll
          for (int nt = 0; nt < 2; ++nt)
            acc_y[mt][nt] = __builtin_amdgcn_mfma_f32_16x16x32_f16(a, bq[nt], acc_y[mt][nt], 0, 0, 0);
        }
      }
      uint2 pn[4][2];
      #pragma unroll
      for (int mt = 0; mt < 4; ++mt)
        #pragma unroll
        for (int nt = 0; nt < 2; ++nt)
          pn[mt][nt] = *(const uint2*)&curT[(w * 32 + nt * 16 + l15) * 72 + mt * 16 + G * 4];
      __syncthreads();
      #pragma unroll
      for (int mt = 0; mt < 4; ++mt)
        #pragma unroll
        for (int nt = 0; nt < 2; ++nt) {
          int f = w * 32 + nt * 16 + l15, i0 = mt * 16 + G * 4;
          uint2 pk; u16* ps = (u16*)&pk;
          const u16* pp = (const u16*)&pm2[mt][nt];
          #pragma unroll
          for (int r = 0; r < 4; ++r) {
            float vv = acc_y[mt][nt][r];
            if (k >= 2) vv = 2.f * vv - h2f(pp[r]);
            ps[r] = f2h(vv);
          }
          *(uint2*)&curT[f * 72 + i0] = pk;
          cur[(i0 + 0) * 136 + f] = ps[0]; cur[(i0 + 1) * 136 + f] = ps[1];
          cur[(i0 + 2) * 136 + f] = ps[2]; cur[(i0 + 3) * 136 + f] = ps[3];
          pm2[mt][nt] = pn[mt][nt];
        }
      __syncthreads();
    }
    // acc_o += T_k @ W1[k]
    #pragma unroll
    for (int ks2 = 0; ks2 < 4; ++ks2) {
      f16x8 a4[4];
      #pragma unroll
      for (int mt = 0; mt < 4; ++mt)
        a4[mt] = *(const f16x8*)&cur[(mt * 16 + l15) * 136 + ks2 * 32 + G * 8];
      #pragma unroll
      for (int nc = 0; nc < 4; ++nc) {
        f16x8 bb = *(const f16x8*)(Wt1 + (size_t)(w * 64 + nc * 16 + l15) * KC1 + k * 128 + ks2 * 32 + G * 8);
        #pragma unroll
        for (int mt = 0; mt < 4; ++mt)
          acc_o[mt][nc] = __builtin_amdgcn_mfma_f32_16x16x32_f16(a4[mt], bb, acc_o[mt][nc], 0, 0, 0);
      }
    }
  }
  // epilogue: h1 = relu(acc_o + b1)
  #pragma unroll
  for (int nc = 0; nc < 4; ++nc) {
    int gc = w * 64 + nc * 16 + l15;
    float bias = b1[gc];
    #pragma unroll
    for (int mt = 0; mt < 4; ++mt) {
      int i0 = mt * 16 + G * 4;
      #pragma unroll
      for (int r = 0; r < 4; ++r) {
        float v = acc_o[mt][nc][r] + bias;
        v = v > 0.f ? v : 0.f;
        h1[(size_t)(g * 64 + i0 + r) * 256 + gc] = f2h(v);
      }
    }
  }
}

// ======== fused stage 2: A-build + MFMA recurrence over h1 + out2-acc + pool + reparameterize ========
// LDS: Ah[64][72] @0 (9216) | cur2[64][264] @9216 (33792) | curT2[256][72] @43008 (36864)
//      sAf aliases @43008 | ideg @79872 | sdis @80128 | smu @80384 (512) | total 80896
__global__ __launch_bounds__(256, 2) void k_stage2(const int* __restrict__ ei, const u16* __restrict__ h1,
                                                   const u16* __restrict__ Wt23, const float* __restrict__ b2,
                                                   const float* __restrict__ b3, const float* __restrict__ eps,
                                                   float* __restrict__ dout, u16* __restrict__ zb) {
  extern __shared__ char sm2[];
  u16* Ah     = (u16*)(sm2 + 0);
  u16* cur2   = (u16*)(sm2 + 9216);
  u16* curT2  = (u16*)(sm2 + 43008);
  float* sAf  = (float*)(sm2 + 43008);
  int* ideg   = (int*)(sm2 + 79872);
  float* sdis = (float*)(sm2 + 80128);
  float* smu  = (float*)(sm2 + 80384);
  int g = blockIdx.x, t = threadIdx.x;
  int lane = t & 63, w = t >> 6, l15 = lane & 15, G = lane >> 4;
  // ---- build Lhat ----
  for (int e = t; e < 64 * 66; e += 256) sAf[e] = 0.f;
  if (t < 64) ideg[t] = 0;
  __syncthreads();
  int sl[4], dl[4];
  #pragma unroll
  for (int u = 0; u < 4; ++u) {
    int idx = g * 1024 + t + u * 256;
    sl[u] = ei[idx] & 63; dl[u] = ei[EDG + idx] & 63;
    atomicAdd(&ideg[sl[u]], 1); atomicAdd(&ideg[dl[u]], 1);
  }
  __syncthreads();
  if (t < 64) sdis[t] = rsqrtf((float)ideg[t]);
  __syncthreads();
  #pragma unroll
  for (int u = 0; u < 4; ++u) {
    float wg = -sdis[sl[u]] * sdis[dl[u]];
    atomicAdd(&sAf[sl[u] * 66 + dl[u]], wg);
    atomicAdd(&sAf[dl[u] * 66 + sl[u]], wg);
  }
  __syncthreads();
  for (int e = t; e < 4096; e += 256) Ah[(e >> 6) * 72 + (e & 63)] = f2h(sAf[(e >> 6) * 66 + (e & 63)]);
  __syncthreads();
  // ---- T0 = h1 -> cur2 + curT2 ----
  const uint4* hg = (const uint4*)(h1 + (size_t)g * 16384);
  #pragma unroll
  for (int p0 = 0; p0 < 8; ++p0) {
    int p = t + p0 * 256;
    int r = p >> 5, c8 = (p & 31) * 8;
    uint4 v = hg[p];
    *(uint4*)&cur2[r * 264 + c8] = v;
    const u16* pv = (const u16*)&v;
    #pragma unroll
    for (int e = 0; e < 8; ++e) curT2[(c8 + e) * 72 + r] = pv[e];
  }
  __syncthreads();
  f32x4 acc_o[4][2];
  #pragma unroll
  for (int m = 0; m < 4; ++m)
    #pragma unroll
    for (int n = 0; n < 2; ++n) acc_o[m][n] = (f32x4){0.f, 0.f, 0.f, 0.f};
  uint2 pm2[4][4];
  #pragma unroll
  for (int m = 0; m < 4; ++m)
    #pragma unroll
    for (int n = 0; n < 4; ++n) pm2[m][n] = (uint2){0u, 0u};

  for (int k = 0; k < 7; ++k) {
    if (k > 0) {
      f32x4 acc_y[4][4];
      #pragma unroll
      for (int m = 0; m < 4; ++m)
        #pragma unroll
        for (int n = 0; n < 4; ++n) acc_y[m][n] = (f32x4){0.f, 0.f, 0.f, 0.f};
      #pragma unroll
      for (int ks = 0; ks < 2; ++ks) {
        f16x8 bq[4];
        #pragma unroll
        for (int nt = 0; nt < 4; ++nt)
          bq[nt] = *(const f16x8*)&curT2[(w * 64 + nt * 16 + l15) * 72 + ks * 32 + G * 8];
        #pragma unroll
        for (int mt = 0; mt < 4; ++mt) {
          f16x8 a = *(const f16x8*)&Ah[(mt * 16 + l15) * 72 + ks * 32 + G * 8];
          #pragma unroll
          for (int nt = 0; nt < 4; ++nt)
            acc_y[mt][nt] = __builtin_amdgcn_mfma_f32_16x16x32_f16(a, bq[nt], acc_y[mt][nt], 0, 0, 0);
        }
      }
      uint2 pn[4][4];
      #pragma unroll
      for (int mt = 0; mt < 4; ++mt)
        #pragma unroll
        for (int nt = 0; nt < 4; ++nt)
          pn[mt][nt] = *(const uint2*)&curT2[(w * 64 + nt * 16 + l15) * 72 + mt * 16 + G * 4];
      __syncthreads();
      #pragma unroll
      for (int mt = 0; mt < 4; ++mt)
        #pragma unroll
        for (int nt = 0; nt < 4; ++nt) {
          int f = w * 64 + nt * 16 + l15, i0 = mt * 16 + G * 4;
          uint2 pk; u16* ps = (u16*)&pk;
          const u16* pp = (const u16*)&pm2[mt][nt];
          #pragma unroll
          for (int r = 0; r < 4; ++r) {
            float vv = acc_y[mt][nt][r];
            if (k >= 2) vv = 2.f * vv - h2f(pp[r]);
            ps[r] = f2h(vv);
          }
          *(uint2*)&curT2[f * 72 + i0] = pk;
          cur2[(i0 + 0) * 264 + f] = ps[0]; cur2[(i0 + 1) * 264 + f] = ps[1];
          cur2[(i0 + 2) * 264 + f] = ps[2]; cur2[(i0 + 3) * 264 + f] = ps[3];
          pm2[mt][nt] = pn[mt][nt];
        }
      __syncthreads();
    }
    // acc_o += T_k @ [W2[k]|W3[k]]
    #pragma unroll
    for (int ks2 = 0; ks2 < 8; ++ks2) {
      f16x8 a4[4];
      #pragma unroll
      for (int mt = 0; mt < 4; ++mt)
        a4[mt] = *(const f16x8*)&cur2[(mt * 16 + l15) * 264 + ks2 * 32 + G * 8];
      #pragma unroll
      for (int nc = 0; nc < 2; ++nc) {
        f16x8 bb = *(const f16x8*)(Wt23 + (size_t)(w * 32 + nc * 16 + l15) * KC2 + k * 256 + ks2 * 32 + G * 8);
        #pragma unroll
        for (int mt = 0; mt < 4; ++mt)
          acc_o[mt][nc] = __builtin_amdgcn_mfma_f32_16x16x32_f16(a4[mt], bb, acc_o[mt][nc], 0, 0, 0);
      }
    }
  }
  // ---- pool (mean over 64 nodes) + reparameterize ----
  #pragma unroll
  for (int nc = 0; nc < 2; ++nc) {
    float s = 0.f;
    #pragma unroll
    for (int mt = 0; mt < 4; ++mt)
      #pragma unroll
      for (int r = 0; r < 4; ++r) s += acc_o[mt][nc][r];
    s += __shfl_xor(s, 16);
    s += __shfl_xor(s, 32);
    if (G == 0) smu[w * 32 + nc * 16 + l15] = s;
  }
  __syncthreads();
  if (t < 64) {
    float m = smu[t] * (1.f / 64.f) + b2[t];
    float l = smu[64 + t] * (1.f / 64.f) + b3[t];
    float z = m + eps[g * 64 + t] * expf(0.5f * l);
    dout[1032192 + g * 64 + t] = m;
    dout[1032192 + 32768 + g * 64 + t] = l;
    zb[g * 64 + t] = f2h(z);
  }
}

// ---------------- MFMA TN GEMM (head, f16): C[M][ldc] = A[M][lda] * Bt[N][ldb]^T ----------------
// EPI 0: bias+relu -> f16 ; 3: bias+sigmoid -> f32, guard N<2016
template <int EPI>
__global__ __launch_bounds__(256) void k_gemm_tn(const u16* __restrict__ A, int lda,
                                                 const u16* __restrict__ Bt, int ldb, int K,
                                                 const float* __restrict__ bias_a,
                                                 u16* __restrict__ Chf, float* __restrict__ Cf32, int ldc) {
  __shared__ __align__(16) u16 As[2][128 * 40];
  __shared__ __align__(16) u16 Bs[2][128 * 40];
  int t = threadIdx.x;
  int lane = t & 63, wave = t >> 6;
  int wr = wave >> 1, wc = wave & 1;
  int bm = blockIdx.x * 128, bn = blockIdx.y * 128;
  int ra = t >> 1, ka = (t & 1) * 16;
  const u16* Ap = A + (size_t)(bm + ra) * lda + ka;
  const u16* Bp = Bt + (size_t)(bn + ra) * ldb + ka;

  f32x4 acc[4][4];
  #pragma unroll
  for (int m = 0; m < 4; ++m)
    #pragma unroll
    for (int n = 0; n < 4; ++n) acc[m][n] = (f32x4){0.f, 0.f, 0.f, 0.f};

  int nk = K >> 5;
  {
    uint4 a0 = *(const uint4*)(Ap), a1 = *(const uint4*)(Ap + 8);
    uint4 b0 = *(const uint4*)(Bp), b1 = *(const uint4*)(Bp + 8);
    *(uint4*)&As[0][ra * 40 + ka] = a0; *(uint4*)&As[0][ra * 40 + ka + 8] = a1;
    *(uint4*)&Bs[0][ra * 40 + ka] = b0; *(uint4*)&Bs[0][ra * 40 + ka + 8] = b1;
  }
  for (int ks = 0; ks < nk; ++ks) {
    int cu = ks & 1;
    uint4 na0, na1, nb0, nb1;
    bool pf = (ks + 1 < nk);
    if (pf) {
      int k0 = (ks + 1) << 5;
      na0 = *(const uint4*)(Ap + k0); na1 = *(const uint4*)(Ap + k0 + 8);
      nb0 = *(const uint4*)(Bp + k0); nb1 = *(const uint4*)(Bp + k0 + 8);
    }
    __syncthreads();
    f16x8 af[4], bfr[4];
    #pragma unroll
    for (int m = 0; m < 4; ++m)
      af[m] = *(const f16x8*)&As[cu][(wr * 64 + m * 16 + (lane & 15)) * 40 + (lane >> 4) * 8];
    #pragma unroll
    for (int n = 0; n < 4; ++n)
      bfr[n] = *(const f16x8*)&Bs[cu][(wc * 64 + n * 16 + (lane & 15)) * 40 + (lane >> 4) * 8];
    #pragma unroll
    for (int m = 0; m < 4; ++m)
      #pragma unroll
      for (int n = 0; n < 4; ++n)
        acc[m][n] = __builtin_amdgcn_mfma_f32_16x16x32_f16(af[m], bfr[n], acc[m][n], 0, 0, 0);
    if (pf) {
      int nb = (ks + 1) & 1;
      __syncthreads();
      *(uint4*)&As[nb][ra * 40 + ka] = na0; *(uint4*)&As[nb][ra * 40 + ka + 8] = na1;
      *(uint4*)&Bs[nb][ra * 40 + ka] = nb0; *(uint4*)&Bs[nb][ra * 40 + ka + 8] = nb1;
    }
  }
  #pragma unroll
  for (int n = 0; n < 4; ++n) {
    int gcol = bn + wc * 64 + n * 16 + (lane & 15);
    float bias = (EPI == 3) ? ((gcol < 2016) ? bias_a[gcol] : 0.f) : bias_a[gcol];
    #pragma unroll
    for (int m = 0; m < 4; ++m) {
      int grow0 = bm + wr * 64 + m * 16 + (lane >> 4) * 4;
      #pragma unroll
      for (int r = 0; r < 4; ++r) {
        float v = acc[m][n][r];
        size_t off = (size_t)(grow0 + r) * ldc + gcol;
        if (EPI == 0) { v += bias; v = v > 0.f ? v : 0.f; Chf[off] = f2h(v); }
        else { if (gcol < 2016) { v += bias; Cf32[off] = 1.f / (1.f + expf(-v)); } }
      }
    }
  }
}

// ---------------- host launch ----------------
extern "C" void kernel_launch(void* const* d_in, const int* in_sizes, int n_in,
                              void* d_out, int out_size, void* d_ws, size_t ws_size,
                              hipStream_t stream) {
  const float* x   = (const float*)d_in[0];
  const int*   ei  = (const int*)d_in[1];
  const float* eps = (const float*)d_in[3];
  const float* W1  = (const float*)d_in[4];  const float* b1  = (const float*)d_in[5];
  const float* W2  = (const float*)d_in[6];  const float* b2  = (const float*)d_in[7];
  const float* W3  = (const float*)d_in[8];  const float* b3  = (const float*)d_in[9];
  const float* Wf1 = (const float*)d_in[10]; const float* bf1 = (const float*)d_in[11];
  const float* Wf2 = (const float*)d_in[12]; const float* bf2v= (const float*)d_in[13];
  float* dout = (float*)d_out;
  char* ws = (char*)d_ws;

  // workspace: 19,103,744 bytes
  u16* Wt1  = (u16*)(ws + 0);         //   458,752  [256][896]
  u16* Wt23 = (u16*)(ws + 458752);    //   458,752  [128][1792]
  u16* Wf1t = (u16*)(ws + 917504);    //    32,768  [256][64]
  u16* Wf2t = (u16*)(ws + 950272);    // 1,048,576  [2048][256]
  u16* zb   = (u16*)(ws + 1998848);   //    65,536  [512][64]
  u16* hh   = (u16*)(ws + 2064384);   //   262,144  [512][256]
  u16* h1   = (u16*)(ws + 2326528);   // 16,777,216 [32768][256]

  k_prep  <<<dim3(3904), dim3(256), 0, stream>>>(W1, W2, W3, Wf1, Wf2, Wt1, Wt23, Wf1t, Wf2t);
  k_stage1<<<dim3(NGR),  dim3(256), 45568, stream>>>(ei, x, Wt1, b1, h1);
  k_stage2<<<dim3(NGR),  dim3(256), 80896, stream>>>(ei, h1, Wt23, b2, b3, eps, dout, zb);
  k_gemm_tn<0><<<dim3(4, 2),  dim3(256), 0, stream>>>(zb, 64, Wf1t, 64, 64, bf1, hh, nullptr, 256);
  k_gemm_tn<3><<<dim3(4, 16), dim3(256), 0, stream>>>(hh, 256, Wf2t, 256, 256, bf2v, nullptr, dout, 2016);
}

// Round 13
// 116.936 us; speedup vs baseline: 2.9713x; 1.0802x over previous
//
#include <hip/hip_runtime.h>

typedef unsigned int uint;
typedef unsigned short u16;
typedef _Float16 f16;
typedef __attribute__((ext_vector_type(8))) _Float16 f16x8;
typedef __attribute__((ext_vector_type(4))) float f32x4;

#define NGR 512
#define EDG 1048576

union uhcv { u16 u; f16 h; };
__device__ __forceinline__ u16 f2h(float f) { uhcv x; x.h = (f16)f; return x.u; }
__device__ __forceinline__ float h2f(u16 v) { uhcv x; x.u = v; return (float)x.h; }

// ---------------- coalesced tiled transpose f32 -> f16: dst[c][r] = src[r][c] ----------------
template<int R, int C, int SPLIT>
__global__ __launch_bounds__(256) void k_tr(const float* __restrict__ A, const float* __restrict__ B,
                                            u16* __restrict__ dst) {
  __shared__ u16 tile[64][68];
  int r0 = blockIdx.x * 64, c0 = blockIdx.y * 64;
  int t = threadIdx.x;
  int cl = t & 63, rl = t >> 6;
  #pragma unroll
  for (int pass = 0; pass < 16; ++pass) {
    int r = r0 + rl + pass * 4, c = c0 + cl;
    float v = 0.f;
    if (r < R && c < C) {
      if (SPLIT != 0 && c >= SPLIT) v = B[(size_t)r * SPLIT + (c - SPLIT)];
      else v = A[(size_t)r * (SPLIT != 0 ? SPLIT : C) + c];
    }
    tile[cl][rl + pass * 4] = f2h(v);
  }
  __syncthreads();
  int nl = t >> 2, rs = (t & 3) * 16;
  #pragma unroll
  for (int j = 0; j < 4; ++j) {
    uint2 v = *(const uint2*)&tile[nl][rs + j * 4];
    *(uint2*)&dst[(size_t)(c0 + nl) * R + r0 + rs + j * 4] = v;
  }
}

// ---------------- per-graph dense 2*Lhat (f16, [512][64][64]) ----------------
__global__ __launch_bounds__(256) void k_buildA(const int* __restrict__ ei, u16* __restrict__ Ah2) {
  int g = blockIdx.x, t = threadIdx.x;
  __shared__ float sA[64 * 66];
  __shared__ int ideg[64];
  __shared__ float sdis[64];
  for (int e = t; e < 64 * 66; e += 256) sA[e] = 0.f;
  if (t < 64) ideg[t] = 0;
  __syncthreads();
  int sl[4], dl[4];
  #pragma unroll
  for (int u = 0; u < 4; ++u) {
    int idx = g * 1024 + t + u * 256;
    sl[u] = ei[idx] & 63; dl[u] = ei[EDG + idx] & 63;
    atomicAdd(&ideg[sl[u]], 1); atomicAdd(&ideg[dl[u]], 1);
  }
  __syncthreads();
  if (t < 64) sdis[t] = rsqrtf((float)ideg[t]);
  __syncthreads();
  #pragma unroll
  for (int u = 0; u < 4; ++u) {
    float wg = -sdis[sl[u]] * sdis[dl[u]];
    atomicAdd(&sA[sl[u] * 66 + dl[u]], wg);
    atomicAdd(&sA[dl[u] * 66 + sl[u]], wg);
  }
  __syncthreads();
  for (int e = t; e < 4096; e += 256)
    Ah2[(size_t)g * 4096 + e] = f2h(2.f * sA[(e >> 6) * 66 + (e & 63)]);
}

// ======== fused main: both Cheb stages per graph, h1 stays in LDS; pool+reparam+MLP1 tail ========
// LDS: Ah[64][72] @0 | cur[64][264] @9216 (node-major) | curT[256][72] @43008 (feat-major)
//      smu[128] @79872 | sz[64] @80384 | total 80640 -> 2 blocks/CU
__global__ __launch_bounds__(512, 4) void k_main(
    const u16* __restrict__ Ah2, const float* __restrict__ x,
    const u16* __restrict__ Wt1, const float* __restrict__ b1,
    const u16* __restrict__ Wt23, const float* __restrict__ b2, const float* __restrict__ b3,
    const float* __restrict__ eps, const float* __restrict__ Wf1, const float* __restrict__ bf1,
    float* __restrict__ dout, u16* __restrict__ hh) {
  extern __shared__ char smem[];
  u16* Ah    = (u16*)(smem);
  u16* cur   = (u16*)(smem + 9216);
  u16* curT  = (u16*)(smem + 43008);
  float* smu = (float*)(smem + 79872);
  float* sz  = (float*)(smem + 80384);
  int g = blockIdx.x, t = threadIdx.x;
  int lane = t & 63, w = t >> 6, l15 = lane & 15, G = lane >> 4;

  // stage 2*Lhat (512 uint4 = one pass of 512 threads) and T0 = x (128 feats)
  {
    const uint4* src = (const uint4*)(Ah2 + (size_t)g * 4096);
    {
      int p = t;                       // 512 uint4 total — exactly one pass
      int r = p >> 3, c8 = (p & 7) * 8;
      *(uint4*)&Ah[r * 72 + c8] = src[p];
    }
    const float4* xg = (const float4*)(x + (size_t)g * 8192);
    #pragma unroll
    for (int i = 0; i < 4; ++i) {
      int p = t + i * 512;
      int r = p >> 5, c4 = (p & 31) * 4;
      float4 v = xg[p];
      u16 e0 = f2h(v.x), e1 = f2h(v.y), e2 = f2h(v.z), e3 = f2h(v.w);
      uint2 pk; u16* ps = (u16*)&pk; ps[0] = e0; ps[1] = e1; ps[2] = e2; ps[3] = e3;
      *(uint2*)&cur[r * 264 + c4] = pk;
      curT[(c4 + 0) * 72 + r] = e0; curT[(c4 + 1) * 72 + r] = e1;
      curT[(c4 + 2) * 72 + r] = e2; curT[(c4 + 3) * 72 + r] = e3;
    }
  }
  __syncthreads();

  // ===== phase 1: h1 = relu(sum_k T_k @ W1[k] + b1) =====
  f32x4 accA[4][2];
  #pragma unroll
  for (int m = 0; m < 4; ++m) { accA[m][0] = (f32x4){0,0,0,0}; accA[m][1] = (f32x4){0,0,0,0}; }
  uint2 pA[4], pB[4];
  #pragma unroll
  for (int m = 0; m < 4; ++m) {
    pA[m] = *(const uint2*)&curT[(w * 16 + l15) * 72 + m * 16 + G * 4];
    pB[m] = pA[m];
  }

  for (int k = 1; k <= 7; ++k) {
    // consume T_{k-1} with W1[k-1]  (global W stream overlaps the recurrence MFMAs)
    #pragma unroll
    for (int ks = 0; ks < 4; ++ks) {
      f16x8 bb0 = *(const f16x8*)(Wt1 + (size_t)(w * 32 + l15) * 896 + (k - 1) * 128 + ks * 32 + G * 8);
      f16x8 bb1 = *(const f16x8*)(Wt1 + (size_t)(w * 32 + 16 + l15) * 896 + (k - 1) * 128 + ks * 32 + G * 8);
      #pragma unroll
      for (int m = 0; m < 4; ++m) {
        f16x8 a4 = *(const f16x8*)&cur[(m * 16 + l15) * 264 + ks * 32 + G * 8];
        accA[m][0] = __builtin_amdgcn_mfma_f32_16x16x32_f16(a4, bb0, accA[m][0], 0, 0, 0);
        accA[m][1] = __builtin_amdgcn_mfma_f32_16x16x32_f16(a4, bb1, accA[m][1], 0, 0, 0);
      }
    }
    if (k == 7) break;
    // T_k = (2L)@T_{k-1} - T_{k-2}: seed acc with -T_{k-2}; k==1 -> seed 0, scale 0.5
    f32x4 accY[4];
    #pragma unroll
    for (int m = 0; m < 4; ++m) {
      const u16* pp = (const u16*)&pB[m];
      #pragma unroll
      for (int r = 0; r < 4; ++r) accY[m][r] = (k >= 2) ? -h2f(pp[r]) : 0.f;
    }
    #pragma unroll
    for (int ks = 0; ks < 2; ++ks) {
      f16x8 bq = *(const f16x8*)&curT[(w * 16 + l15) * 72 + ks * 32 + G * 8];
      #pragma unroll
      for (int m = 0; m < 4; ++m) {
        f16x8 a = *(const f16x8*)&Ah[(m * 16 + l15) * 72 + ks * 32 + G * 8];
        accY[m] = __builtin_amdgcn_mfma_f32_16x16x32_f16(a, bq, accY[m], 0, 0, 0);
      }
    }
    __syncthreads();
    {
      int f = w * 16 + l15;
      float sc = (k == 1) ? 0.5f : 1.f;
      #pragma unroll
      for (int m = 0; m < 4; ++m) {
        int i0 = m * 16 + G * 4;
        uint2 pk; u16* ps = (u16*)&pk;
        #pragma unroll
        for (int r = 0; r < 4; ++r) ps[r] = f2h(sc * accY[m][r]);
        *(uint2*)&curT[f * 72 + i0] = pk;
        cur[(i0 + 0) * 264 + f] = ps[0]; cur[(i0 + 1) * 264 + f] = ps[1];
        cur[(i0 + 2) * 264 + f] = ps[2]; cur[(i0 + 3) * 264 + f] = ps[3];
        pB[m] = pA[m]; pA[m] = pk;
      }
    }
    __syncthreads();
  }
  __syncthreads();   // cons(T6) reads complete before h1 overwrites LDS

  // h1 epilogue -> phase-2 T0 (LDS + packed frags; phase-2 ownership == phase-1 output cols)
  uint2 pA2[4][2], pB2[4][2];
  #pragma unroll
  for (int nc = 0; nc < 2; ++nc) {
    int gc = w * 32 + nc * 16 + l15;
    float bias = b1[gc];
    #pragma unroll
    for (int m = 0; m < 4; ++m) {
      int i0 = m * 16 + G * 4;
      uint2 pk; u16* ps = (u16*)&pk;
      #pragma unroll
      for (int r = 0; r < 4; ++r) {
        float v = accA[m][nc][r] + bias;
        ps[r] = f2h(v > 0.f ? v : 0.f);
      }
      *(uint2*)&curT[gc * 72 + i0] = pk;
      cur[(i0 + 0) * 264 + gc] = ps[0]; cur[(i0 + 1) * 264 + gc] = ps[1];
      cur[(i0 + 2) * 264 + gc] = ps[2]; cur[(i0 + 3) * 264 + gc] = ps[3];
      pA2[m][nc] = pk; pB2[m][nc] = pk;
    }
  }
  __syncthreads();

  // ===== phase 2: out2 = sum_k T_k @ [W2|W3][k], T over h1 (256 feats) =====
  f32x4 accB[4];
  #pragma unroll
  for (int m = 0; m < 4; ++m) accB[m] = (f32x4){0,0,0,0};
  for (int k = 1; k <= 7; ++k) {
    #pragma unroll
    for (int ks = 0; ks < 8; ++ks) {
      f16x8 bb = *(const f16x8*)(Wt23 + (size_t)(w * 16 + l15) * 1792 + (k - 1) * 256 + ks * 32 + G * 8);
      #pragma unroll
      for (int m = 0; m < 4; ++m) {
        f16x8 a4 = *(const f16x8*)&cur[(m * 16 + l15) * 264 + ks * 32 + G * 8];
        accB[m] = __builtin_amdgcn_mfma_f32_16x16x32_f16(a4, bb, accB[m], 0, 0, 0);
      }
    }
    if (k == 7) break;
    f32x4 accY[4][2];
    #pragma unroll
    for (int m = 0; m < 4; ++m)
      #pragma unroll
      for (int nt = 0; nt < 2; ++nt) {
        const u16* pp = (const u16*)&pB2[m][nt];
        #pragma unroll
        for (int r = 0; r < 4; ++r) accY[m][nt][r] = (k >= 2) ? -h2f(pp[r]) : 0.f;
      }
    #pragma unroll
    for (int ks = 0; ks < 2; ++ks) {
      f16x8 bq0 = *(const f16x8*)&curT[(w * 32 + l15) * 72 + ks * 32 + G * 8];
      f16x8 bq1 = *(const f16x8*)&curT[(w * 32 + 16 + l15) * 72 + ks * 32 + G * 8];
      #pragma unroll
      for (int m = 0; m < 4; ++m) {
        f16x8 a = *(const f16x8*)&Ah[(m * 16 + l15) * 72 + ks * 32 + G * 8];
        accY[m][0] = __builtin_amdgcn_mfma_f32_16x16x32_f16(a, bq0, accY[m][0], 0, 0, 0);
        accY[m][1] = __builtin_amdgcn_mfma_f32_16x16x32_f16(a, bq1, accY[m][1], 0, 0, 0);
      }
    }
    __syncthreads();
    {
      float sc = (k == 1) ? 0.5f : 1.f;
      #pragma unroll
      for (int nt = 0; nt < 2; ++nt) {
        int f = w * 32 + nt * 16 + l15;
        #pragma unroll
        for (int m = 0; m < 4; ++m) {
          int i0 = m * 16 + G * 4;
          uint2 pk; u16* ps = (u16*)&pk;
          #pragma unroll
          for (int r = 0; r < 4; ++r) ps[r] = f2h(sc * accY[m][nt][r]);
          *(uint2*)&curT[f * 72 + i0] = pk;
          cur[(i0 + 0) * 264 + f] = ps[0]; cur[(i0 + 1) * 264 + f] = ps[1];
          cur[(i0 + 2) * 264 + f] = ps[2]; cur[(i0 + 3) * 264 + f] = ps[3];
          pB2[m][nt] = pA2[m][nt]; pA2[m][nt] = pk;
        }
      }
    }
    __syncthreads();
  }
  // ---- pool over 64 nodes + reparameterize + MLP1 ----
  {
    float s0 = 0.f;
    #pragma unroll
    for (int m = 0; m < 4; ++m)
      #pragma unroll
      for (int r = 0; r < 4; ++r) s0 += accB[m][r];
    s0 += __shfl_xor(s0, 16);
    s0 += __shfl_xor(s0, 32);
    if (G == 0) smu[w * 16 + l15] = s0;
  }
  __syncthreads();
  if (t < 64) {
    float m = smu[t] * (1.f / 64.f) + b2[t];
    float l = smu[64 + t] * (1.f / 64.f) + b3[t];
    float z = m + eps[g * 64 + t] * expf(0.5f * l);
    dout[1032192 + g * 64 + t] = m;
    dout[1032192 + 32768 + g * 64 + t] = l;
    sz[t] = z;
  }
  __syncthreads();
  if (t < 256) {
    float aq = bf1[t];
    #pragma unroll 8
    for (int j = 0; j < 64; ++j) aq += sz[j] * Wf1[j * 256 + t];
    hh[(size_t)g * 256 + t] = f2h(aq > 0.f ? aq : 0.f);
  }
}

// ---------------- sigmoid GEMM: adj = sigmoid(hh[512][256] @ Wf2t^T + bf2) ----------------
__global__ __launch_bounds__(256) void k_gemm_sig(const u16* __restrict__ A,
                                                  const u16* __restrict__ Bt,
                                                  const float* __restrict__ bias_a,
                                                  float* __restrict__ Cf32) {
  __shared__ __align__(16) u16 As[2][128 * 40];
  __shared__ __align__(16) u16 Bs[2][128 * 40];
  int t = threadIdx.x;
  int lane = t & 63, wave = t >> 6;
  int wr = wave >> 1, wc = wave & 1;
  int bm = blockIdx.x * 128, bn = blockIdx.y * 128;
  int ra = t >> 1, ka = (t & 1) * 16;
  const u16* Ap = A + (size_t)(bm + ra) * 256 + ka;
  const u16* Bp = Bt + (size_t)(bn + ra) * 256 + ka;

  f32x4 acc[4][4];
  #pragma unroll
  for (int m = 0; m < 4; ++m)
    #pragma unroll
    for (int n = 0; n < 4; ++n) acc[m][n] = (f32x4){0.f, 0.f, 0.f, 0.f};

  {
    uint4 a0 = *(const uint4*)(Ap), a1 = *(const uint4*)(Ap + 8);
    uint4 b0 = *(const uint4*)(Bp), b1 = *(const uint4*)(Bp + 8);
    *(uint4*)&As[0][ra * 40 + ka] = a0; *(uint4*)&As[0][ra * 40 + ka + 8] = a1;
    *(uint4*)&Bs[0][ra * 40 + ka] = b0; *(uint4*)&Bs[0][ra * 40 + ka + 8] = b1;
  }
  for (int ks = 0; ks < 8; ++ks) {
    int cu = ks & 1;
    uint4 na0, na1, nb0, nb1;
    bool pf = (ks + 1 < 8);
    if (pf) {
      int k0 = (ks + 1) << 5;
      na0 = *(const uint4*)(Ap + k0); na1 = *(const uint4*)(Ap + k0 + 8);
      nb0 = *(const uint4*)(Bp + k0); nb1 = *(const uint4*)(Bp + k0 + 8);
    }
    __syncthreads();
    f16x8 af[4], bfr[4];
    #pragma unroll
    for (int m = 0; m < 4; ++m)
      af[m] = *(const f16x8*)&As[cu][(wr * 64 + m * 16 + (lane & 15)) * 40 + (lane >> 4) * 8];
    #pragma unroll
    for (int n = 0; n < 4; ++n)
      bfr[n] = *(const f16x8*)&Bs[cu][(wc * 64 + n * 16 + (lane & 15)) * 40 + (lane >> 4) * 8];
    #pragma unroll
    for (int m = 0; m < 4; ++m)
      #pragma unroll
      for (int n = 0; n < 4; ++n)
        acc[m][n] = __builtin_amdgcn_mfma_f32_16x16x32_f16(af[m], bfr[n], acc[m][n], 0, 0, 0);
    if (pf) {
      int nb = (ks + 1) & 1;
      __syncthreads();
      *(uint4*)&As[nb][ra * 40 + ka] = na0; *(uint4*)&As[nb][ra * 40 + ka + 8] = na1;
      *(uint4*)&Bs[nb][ra * 40 + ka] = nb0; *(uint4*)&Bs[nb][ra * 40 + ka + 8] = nb1;
    }
  }
  #pragma unroll
  for (int n = 0; n < 4; ++n) {
    int gcol = bn + wc * 64 + n * 16 + (lane & 15);
    if (gcol >= 2016) continue;
    float bias = bias_a[gcol];
    #pragma unroll
    for (int m = 0; m < 4; ++m) {
      int grow0 = bm + wr * 64 + m * 16 + (lane >> 4) * 4;
      #pragma unroll
      for (int r = 0; r < 4; ++r) {
        float v = acc[m][n][r] + bias;
        Cf32[(size_t)(grow0 + r) * 2016 + gcol] = 1.f / (1.f + expf(-v));
      }
    }
  }
}

// ---------------- host launch ----------------
extern "C" void kernel_launch(void* const* d_in, const int* in_sizes, int n_in,
                              void* d_out, int out_size, void* d_ws, size_t ws_size,
                              hipStream_t stream) {
  const float* x   = (const float*)d_in[0];
  const int*   ei  = (const int*)d_in[1];
  const float* eps = (const float*)d_in[3];
  const float* W1  = (const float*)d_in[4];  const float* b1  = (const float*)d_in[5];
  const float* W2  = (const float*)d_in[6];  const float* b2  = (const float*)d_in[7];
  const float* W3  = (const float*)d_in[8];  const float* b3  = (const float*)d_in[9];
  const float* Wf1 = (const float*)d_in[10]; const float* bf1 = (const float*)d_in[11];
  const float* Wf2 = (const float*)d_in[12]; const float* bf2v= (const float*)d_in[13];
  float* dout = (float*)d_out;
  char* ws = (char*)d_ws;

  // workspace: 6,422,528 bytes
  u16* Ah2  = (u16*)(ws + 0);         // 4,194,304  [512][64][64] f16 = 2*Lhat
  u16* Wt1  = (u16*)(ws + 4194304);   //   458,752  [256][896]
  u16* Wt23 = (u16*)(ws + 4653056);   //   458,752  [128][1792]
  u16* Wf2t = (u16*)(ws + 5111808);   // 1,048,576  [2048][256]
  u16* hh   = (u16*)(ws + 6160384);   //   262,144  [512][256]

  k_tr<896, 256, 0>  <<<dim3(14, 4),  dim3(256), 0, stream>>>(W1, nullptr, Wt1);
  k_tr<1792, 128, 64><<<dim3(28, 2),  dim3(256), 0, stream>>>(W2, W3, Wt23);
  k_tr<256, 2016, 0> <<<dim3(4, 32),  dim3(256), 0, stream>>>(Wf2, nullptr, Wf2t);
  k_buildA<<<dim3(NGR), dim3(256), 0, stream>>>(ei, Ah2);
  k_main  <<<dim3(NGR), dim3(512), 80640, stream>>>(Ah2, x, Wt1, b1, Wt23, b2, b3,
                                                    eps, Wf1, bf1, dout, hh);
  k_gemm_sig<<<dim3(4, 16), dim3(256), 0, stream>>>(hh, Wf2t, bf2v, dout);
}

// Round 14
// 95.692 us; speedup vs baseline: 3.6309x; 1.2220x over previous
//
#include <hip/hip_runtime.h>

typedef unsigned int uint;
typedef unsigned short u16;
typedef _Float16 f16;
typedef __attribute__((ext_vector_type(8))) _Float16 f16x8;
typedef __attribute__((ext_vector_type(4))) float f32x4;

#define NGR 512
#define EDG 1048576

union uhcv { u16 u; f16 h; };
__device__ __forceinline__ u16 f2h(float f) { uhcv x; x.h = (f16)f; return x.u; }
__device__ __forceinline__ float h2f(u16 v) { uhcv x; x.u = v; return (float)x.h; }

// ---------------- fragment-pack weights f32 -> f16 ----------------
// W1p  layout [kk(7)][ks(4)][nt(16)][G(4)][l15(16)][8]  : frag (k,ks,ntile) is 1024 contiguous bytes
// W23p layout [kk(7)][ks(8)][nt(8)] [G(4)][l15(16)][8]
__global__ __launch_bounds__(256) void k_prep(const float* __restrict__ W1, const float* __restrict__ W2,
                                              const float* __restrict__ W3,
                                              u16* __restrict__ W1p, u16* __restrict__ W23p) {
  int b = blockIdx.x, t = threadIdx.x;
  if (b < 112) {                    // W1p: 28672 groups of 8
    int g = b * 256 + t;
    int l15 = g & 15, G = (g >> 4) & 3, nt = (g >> 6) & 15, ksk = g >> 10;  // ksk = kk*4+ks
    int f0 = ksk * 32 + G * 8;      // = kk*128 + ks*32 + G*8
    int n = nt * 16 + l15;
    u16 out[8];
    #pragma unroll
    for (int j = 0; j < 8; ++j) out[j] = f2h(W1[(size_t)(f0 + j) * 256 + n]);
    *(uint4*)&W1p[(size_t)g * 8] = *(uint4*)out;
  } else {                          // W23p: 28672 groups
    int g = (b - 112) * 256 + t;
    int l15 = g & 15, G = (g >> 4) & 3, nt = (g >> 6) & 7, ksk = g >> 9;    // ksk = kk*8+ks
    int f0 = ksk * 32 + G * 8;      // = kk*256 + ks*32 + G*8
    int n = nt * 16 + l15;
    u16 out[8];
    #pragma unroll
    for (int j = 0; j < 8; ++j) {
      int f = f0 + j;
      float v = (n < 64) ? W2[(size_t)f * 64 + n] : W3[(size_t)f * 64 + (n - 64)];
      out[j] = f2h(v);
    }
    *(uint4*)&W23p[(size_t)g * 8] = *(uint4*)out;
  }
}

// ---------------- coalesced tiled transpose f32 -> f16 (head weight only) ----------------
template<int R, int C>
__global__ __launch_bounds__(256) void k_tr(const float* __restrict__ A, u16* __restrict__ dst) {
  __shared__ u16 tile[64][68];
  int r0 = blockIdx.x * 64, c0 = blockIdx.y * 64;
  int t = threadIdx.x;
  int cl = t & 63, rl = t >> 6;
  #pragma unroll
  for (int pass = 0; pass < 16; ++pass) {
    int r = r0 + rl + pass * 4, c = c0 + cl;
    float v = 0.f;
    if (r < R && c < C) v = A[(size_t)r * C + c];
    tile[cl][rl + pass * 4] = f2h(v);
  }
  __syncthreads();
  int nl = t >> 2, rs = (t & 3) * 16;
  #pragma unroll
  for (int j = 0; j < 4; ++j) {
    uint2 v = *(const uint2*)&tile[nl][rs + j * 4];
    *(uint2*)&dst[(size_t)(c0 + nl) * R + r0 + rs + j * 4] = v;
  }
}

// ---------------- per-graph dense 2*Lhat (f16, [512][64][64]) ----------------
__global__ __launch_bounds__(256) void k_buildA(const int* __restrict__ ei, u16* __restrict__ Ah2) {
  int g = blockIdx.x, t = threadIdx.x;
  __shared__ float sA[64 * 66];
  __shared__ int ideg[64];
  __shared__ float sdis[64];
  for (int e = t; e < 64 * 66; e += 256) sA[e] = 0.f;
  if (t < 64) ideg[t] = 0;
  __syncthreads();
  int sl[4], dl[4];
  #pragma unroll
  for (int u = 0; u < 4; ++u) {
    int idx = g * 1024 + t + u * 256;
    sl[u] = ei[idx] & 63; dl[u] = ei[EDG + idx] & 63;
    atomicAdd(&ideg[sl[u]], 1); atomicAdd(&ideg[dl[u]], 1);
  }
  __syncthreads();
  if (t < 64) sdis[t] = rsqrtf((float)ideg[t]);
  __syncthreads();
  #pragma unroll
  for (int u = 0; u < 4; ++u) {
    float wg = -sdis[sl[u]] * sdis[dl[u]];
    atomicAdd(&sA[sl[u] * 66 + dl[u]], wg);
    atomicAdd(&sA[dl[u] * 66 + sl[u]], wg);
  }
  __syncthreads();
  for (int e = t; e < 4096; e += 256)
    Ah2[(size_t)g * 4096 + e] = f2h(2.f * sA[(e >> 6) * 66 + (e & 63)]);
}

// ======== fused main: both Cheb stages per graph, h1 stays in LDS; pool+reparam+MLP1 tail ========
// LDS: Ah[64][72] @0 | cur[64][264] @9216 (node-major) | curT[256][72] @43008 (feat-major)
//      smu[128] @79872 | sz[64] @80384 | total 80640 -> 2 blocks/CU
__global__ __launch_bounds__(512, 4) void k_main(
    const u16* __restrict__ Ah2, const float* __restrict__ x,
    const u16* __restrict__ W1p, const float* __restrict__ b1,
    const u16* __restrict__ W23p, const float* __restrict__ b2, const float* __restrict__ b3,
    const float* __restrict__ eps, const float* __restrict__ Wf1, const float* __restrict__ bf1,
    float* __restrict__ dout, u16* __restrict__ hh) {
  extern __shared__ char smem[];
  u16* Ah    = (u16*)(smem);
  u16* cur   = (u16*)(smem + 9216);
  u16* curT  = (u16*)(smem + 43008);
  float* smu = (float*)(smem + 79872);
  float* sz  = (float*)(smem + 80384);
  int g = blockIdx.x, t = threadIdx.x;
  int lane = t & 63, w = t >> 6, l15 = lane & 15, G = lane >> 4;
  int G16l = G * 16 + l15;                     // fragment lane slot (0..63)

  // stage 2*Lhat (512 uint4 = one pass of 512 threads) and T0 = x (128 feats)
  {
    const uint4* src = (const uint4*)(Ah2 + (size_t)g * 4096);
    {
      int p = t;
      int r = p >> 3, c8 = (p & 7) * 8;
      *(uint4*)&Ah[r * 72 + c8] = src[p];
    }
    const float4* xg = (const float4*)(x + (size_t)g * 8192);
    #pragma unroll
    for (int i = 0; i < 4; ++i) {
      int p = t + i * 512;
      int r = p >> 5, c4 = (p & 31) * 4;
      float4 v = xg[p];
      u16 e0 = f2h(v.x), e1 = f2h(v.y), e2 = f2h(v.z), e3 = f2h(v.w);
      uint2 pk; u16* ps = (u16*)&pk; ps[0] = e0; ps[1] = e1; ps[2] = e2; ps[3] = e3;
      *(uint2*)&cur[r * 264 + c4] = pk;
      curT[(c4 + 0) * 72 + r] = e0; curT[(c4 + 1) * 72 + r] = e1;
      curT[(c4 + 2) * 72 + r] = e2; curT[(c4 + 3) * 72 + r] = e3;
    }
  }
  __syncthreads();

  // ===== phase 1: h1 = relu(sum_k T_k @ W1[k] + b1) =====
  f32x4 accA[4][2];
  #pragma unroll
  for (int m = 0; m < 4; ++m) { accA[m][0] = (f32x4){0,0,0,0}; accA[m][1] = (f32x4){0,0,0,0}; }
  uint2 pA[4], pB[4];
  #pragma unroll
  for (int m = 0; m < 4; ++m) {
    pA[m] = *(const uint2*)&curT[(w * 16 + l15) * 72 + m * 16 + G * 4];
    pB[m] = pA[m];
  }

  for (int k = 1; k <= 7; ++k) {
    // consume T_{k-1} with W1[k-1]: fragment-packed, fully-coalesced 1KB wave loads
    #pragma unroll
    for (int ks = 0; ks < 4; ++ks) {
      f16x8 bb0 = *(const f16x8*)(W1p + (size_t)((((k - 1) * 4 + ks) * 16 + (w * 2 + 0)) * 64 + G16l) * 8);
      f16x8 bb1 = *(const f16x8*)(W1p + (size_t)((((k - 1) * 4 + ks) * 16 + (w * 2 + 1)) * 64 + G16l) * 8);
      #pragma unroll
      for (int m = 0; m < 4; ++m) {
        f16x8 a4 = *(const f16x8*)&cur[(m * 16 + l15) * 264 + ks * 32 + G * 8];
        accA[m][0] = __builtin_amdgcn_mfma_f32_16x16x32_f16(a4, bb0, accA[m][0], 0, 0, 0);
        accA[m][1] = __builtin_amdgcn_mfma_f32_16x16x32_f16(a4, bb1, accA[m][1], 0, 0, 0);
      }
    }
    if (k == 7) break;
    // T_k = (2L)@T_{k-1} - T_{k-2}: seed acc with -T_{k-2}; k==1 -> seed 0, scale 0.5
    f32x4 accY[4];
    #pragma unroll
    for (int m = 0; m < 4; ++m) {
      const u16* pp = (const u16*)&pB[m];
      #pragma unroll
      for (int r = 0; r < 4; ++r) accY[m][r] = (k >= 2) ? -h2f(pp[r]) : 0.f;
    }
    #pragma unroll
    for (int ks = 0; ks < 2; ++ks) {
      f16x8 bq = *(const f16x8*)&curT[(w * 16 + l15) * 72 + ks * 32 + G * 8];
      #pragma unroll
      for (int m = 0; m < 4; ++m) {
        f16x8 a = *(const f16x8*)&Ah[(m * 16 + l15) * 72 + ks * 32 + G * 8];
        accY[m] = __builtin_amdgcn_mfma_f32_16x16x32_f16(a, bq, accY[m], 0, 0, 0);
      }
    }
    __syncthreads();
    {
      int f = w * 16 + l15;
      float sc = (k == 1) ? 0.5f : 1.f;
      #pragma unroll
      for (int m = 0; m < 4; ++m) {
        int i0 = m * 16 + G * 4;
        uint2 pk; u16* ps = (u16*)&pk;
        #pragma unroll
        for (int r = 0; r < 4; ++r) ps[r] = f2h(sc * accY[m][r]);
        *(uint2*)&curT[f * 72 + i0] = pk;
        cur[(i0 + 0) * 264 + f] = ps[0]; cur[(i0 + 1) * 264 + f] = ps[1];
        cur[(i0 + 2) * 264 + f] = ps[2]; cur[(i0 + 3) * 264 + f] = ps[3];
        pB[m] = pA[m]; pA[m] = pk;
      }
    }
    __syncthreads();
  }
  __syncthreads();   // cons(T6) reads complete before h1 overwrites LDS

  // h1 epilogue -> phase-2 T0 (LDS + packed frags; phase-2 ownership == phase-1 output cols)
  uint2 pA2[4][2], pB2[4][2];
  #pragma unroll
  for (int nc = 0; nc < 2; ++nc) {
    int gc = w * 32 + nc * 16 + l15;
    float bias = b1[gc];
    #pragma unroll
    for (int m = 0; m < 4; ++m) {
      int i0 = m * 16 + G * 4;
      uint2 pk; u16* ps = (u16*)&pk;
      #pragma unroll
      for (int r = 0; r < 4; ++r) {
        float v = accA[m][nc][r] + bias;
        ps[r] = f2h(v > 0.f ? v : 0.f);
      }
      *(uint2*)&curT[gc * 72 + i0] = pk;
      cur[(i0 + 0) * 264 + gc] = ps[0]; cur[(i0 + 1) * 264 + gc] = ps[1];
      cur[(i0 + 2) * 264 + gc] = ps[2]; cur[(i0 + 3) * 264 + gc] = ps[3];
      pA2[m][nc] = pk; pB2[m][nc] = pk;
    }
  }
  __syncthreads();

  // ===== phase 2: out2 = sum_k T_k @ [W2|W3][k], T over h1 (256 feats) =====
  f32x4 accB[4];
  #pragma unroll
  for (int m = 0; m < 4; ++m) accB[m] = (f32x4){0,0,0,0};
  for (int k = 1; k <= 7; ++k) {
    #pragma unroll
    for (int ks = 0; ks < 8; ++ks) {
      f16x8 bb = *(const f16x8*)(W23p + (size_t)((((k - 1) * 8 + ks) * 8 + w) * 64 + G16l) * 8);
      #pragma unroll
      for (int m = 0; m < 4; ++m) {
        f16x8 a4 = *(const f16x8*)&cur[(m * 16 + l15) * 264 + ks * 32 + G * 8];
        accB[m] = __builtin_amdgcn_mfma_f32_16x16x32_f16(a4, bb, accB[m], 0, 0, 0);
      }
    }
    if (k == 7) break;
    f32x4 accY[4][2];
    #pragma unroll
    for (int m = 0; m < 4; ++m)
      #pragma unroll
      for (int nt = 0; nt < 2; ++nt) {
        const u16* pp = (const u16*)&pB2[m][nt];
        #pragma unroll
        for (int r = 0; r < 4; ++r) accY[m][nt][r] = (k >= 2) ? -h2f(pp[r]) : 0.f;
      }
    #pragma unroll
    for (int ks = 0; ks < 2; ++ks) {
      f16x8 bq0 = *(const f16x8*)&curT[(w * 32 + l15) * 72 + ks * 32 + G * 8];
      f16x8 bq1 = *(const f16x8*)&curT[(w * 32 + 16 + l15) * 72 + ks * 32 + G * 8];
      #pragma unroll
      for (int m = 0; m < 4; ++m) {
        f16x8 a = *(const f16x8*)&Ah[(m * 16 + l15) * 72 + ks * 32 + G * 8];
        accY[m][0] = __builtin_amdgcn_mfma_f32_16x16x32_f16(a, bq0, accY[m][0], 0, 0, 0);
        accY[m][1] = __builtin_amdgcn_mfma_f32_16x16x32_f16(a, bq1, accY[m][1], 0, 0, 0);
      }
    }
    __syncthreads();
    {
      float sc = (k == 1) ? 0.5f : 1.f;
      #pragma unroll
      for (int nt = 0; nt < 2; ++nt) {
        int f = w * 32 + nt * 16 + l15;
        #pragma unroll
        for (int m = 0; m < 4; ++m) {
          int i0 = m * 16 + G * 4;
          uint2 pk; u16* ps = (u16*)&pk;
          #pragma unroll
          for (int r = 0; r < 4; ++r) ps[r] = f2h(sc * accY[m][nt][r]);
          *(uint2*)&curT[f * 72 + i0] = pk;
          cur[(i0 + 0) * 264 + f] = ps[0]; cur[(i0 + 1) * 264 + f] = ps[1];
          cur[(i0 + 2) * 264 + f] = ps[2]; cur[(i0 + 3) * 264 + f] = ps[3];
          pB2[m][nt] = pA2[m][nt]; pA2[m][nt] = pk;
        }
      }
    }
    __syncthreads();
  }
  // ---- pool over 64 nodes + reparameterize + MLP1 ----
  {
    float s0 = 0.f;
    #pragma unroll
    for (int m = 0; m < 4; ++m)
      #pragma unroll
      for (int r = 0; r < 4; ++r) s0 += accB[m][r];
    s0 += __shfl_xor(s0, 16);
    s0 += __shfl_xor(s0, 32);
    if (G == 0) smu[w * 16 + l15] = s0;
  }
  __syncthreads();
  if (t < 64) {
    float m = smu[t] * (1.f / 64.f) + b2[t];
    float l = smu[64 + t] * (1.f / 64.f) + b3[t];
    float z = m + eps[g * 64 + t] * expf(0.5f * l);
    dout[1032192 + g * 64 + t] = m;
    dout[1032192 + 32768 + g * 64 + t] = l;
    sz[t] = z;
  }
  __syncthreads();
  if (t < 256) {
    float aq = bf1[t];
    #pragma unroll 8
    for (int j = 0; j < 64; ++j) aq += sz[j] * Wf1[j * 256 + t];
    hh[(size_t)g * 256 + t] = f2h(aq > 0.f ? aq : 0.f);
  }
}

// ---------------- sigmoid GEMM: adj = sigmoid(hh[512][256] @ Wf2t^T + bf2) ----------------
__global__ __launch_bounds__(256) void k_gemm_sig(const u16* __restrict__ A,
                                                  const u16* __restrict__ Bt,
                                                  const float* __restrict__ bias_a,
                                                  float* __restrict__ Cf32) {
  __shared__ __align__(16) u16 As[2][128 * 40];
  __shared__ __align__(16) u16 Bs[2][128 * 40];
  int t = threadIdx.x;
  int lane = t & 63, wave = t >> 6;
  int wr = wave >> 1, wc = wave & 1;
  int bm = blockIdx.x * 128, bn = blockIdx.y * 128;
  int ra = t >> 1, ka = (t & 1) * 16;
  const u16* Ap = A + (size_t)(bm + ra) * 256 + ka;
  const u16* Bp = Bt + (size_t)(bn + ra) * 256 + ka;

  f32x4 acc[4][4];
  #pragma unroll
  for (int m = 0; m < 4; ++m)
    #pragma unroll
    for (int n = 0; n < 4; ++n) acc[m][n] = (f32x4){0.f, 0.f, 0.f, 0.f};

  {
    uint4 a0 = *(const uint4*)(Ap), a1 = *(const uint4*)(Ap + 8);
    uint4 b0 = *(const uint4*)(Bp), b1 = *(const uint4*)(Bp + 8);
    *(uint4*)&As[0][ra * 40 + ka] = a0; *(uint4*)&As[0][ra * 40 + ka + 8] = a1;
    *(uint4*)&Bs[0][ra * 40 + ka] = b0; *(uint4*)&Bs[0][ra * 40 + ka + 8] = b1;
  }
  for (int ks = 0; ks < 8; ++ks) {
    int cu = ks & 1;
    uint4 na0, na1, nb0, nb1;
    bool pf = (ks + 1 < 8);
    if (pf) {
      int k0 = (ks + 1) << 5;
      na0 = *(const uint4*)(Ap + k0); na1 = *(const uint4*)(Ap + k0 + 8);
      nb0 = *(const uint4*)(Bp + k0); nb1 = *(const uint4*)(Bp + k0 + 8);
    }
    __syncthreads();
    f16x8 af[4], bfr[4];
    #pragma unroll
    for (int m = 0; m < 4; ++m)
      af[m] = *(const f16x8*)&As[cu][(wr * 64 + m * 16 + (lane & 15)) * 40 + (lane >> 4) * 8];
    #pragma unroll
    for (int n = 0; n < 4; ++n)
      bfr[n] = *(const f16x8*)&Bs[cu][(wc * 64 + n * 16 + (lane & 15)) * 40 + (lane >> 4) * 8];
    #pragma unroll
    for (int m = 0; m < 4; ++m)
      #pragma unroll
      for (int n = 0; n < 4; ++n)
        acc[m][n] = __builtin_amdgcn_mfma_f32_16x16x32_f16(af[m], bfr[n], acc[m][n], 0, 0, 0);
    if (pf) {
      int nb = (ks + 1) & 1;
      __syncthreads();
      *(uint4*)&As[nb][ra * 40 + ka] = na0; *(uint4*)&As[nb][ra * 40 + ka + 8] = na1;
      *(uint4*)&Bs[nb][ra * 40 + ka] = nb0; *(uint4*)&Bs[nb][ra * 40 + ka + 8] = nb1;
    }
  }
  #pragma unroll
  for (int n = 0; n < 4; ++n) {
    int gcol = bn + wc * 64 + n * 16 + (lane & 15);
    if (gcol >= 2016) continue;
    float bias = bias_a[gcol];
    #pragma unroll
    for (int m = 0; m < 4; ++m) {
      int grow0 = bm + wr * 64 + m * 16 + (lane >> 4) * 4;
      #pragma unroll
      for (int r = 0; r < 4; ++r) {
        float v = acc[m][n][r] + bias;
        Cf32[(size_t)(grow0 + r) * 2016 + gcol] = 1.f / (1.f + expf(-v));
      }
    }
  }
}

// ---------------- host launch ----------------
extern "C" void kernel_launch(void* const* d_in, const int* in_sizes, int n_in,
                              void* d_out, int out_size, void* d_ws, size_t ws_size,
                              hipStream_t stream) {
  const float* x   = (const float*)d_in[0];
  const int*   ei  = (const int*)d_in[1];
  const float* eps = (const float*)d_in[3];
  const float* W1  = (const float*)d_in[4];  const float* b1  = (const float*)d_in[5];
  const float* W2  = (const float*)d_in[6];  const float* b2  = (const float*)d_in[7];
  const float* W3  = (const float*)d_in[8];  const float* b3  = (const float*)d_in[9];
  const float* Wf1 = (const float*)d_in[10]; const float* bf1 = (const float*)d_in[11];
  const float* Wf2 = (const float*)d_in[12]; const float* bf2v= (const float*)d_in[13];
  float* dout = (float*)d_out;
  char* ws = (char*)d_ws;

  // workspace: 6,422,528 bytes
  u16* Ah2  = (u16*)(ws + 0);         // 4,194,304  [512][64][64] f16 = 2*Lhat
  u16* W1p  = (u16*)(ws + 4194304);   //   458,752  fragment-packed W1
  u16* W23p = (u16*)(ws + 4653056);   //   458,752  fragment-packed [W2|W3]
  u16* Wf2t = (u16*)(ws + 5111808);   // 1,048,576  [2048][256]
  u16* hh   = (u16*)(ws + 6160384);   //   262,144  [512][256]

  k_prep<<<dim3(224), dim3(256), 0, stream>>>(W1, W2, W3, W1p, W23p);
  k_tr<256, 2016><<<dim3(4, 32), dim3(256), 0, stream>>>(Wf2, Wf2t);
  k_buildA<<<dim3(NGR), dim3(256), 0, stream>>>(ei, Ah2);
  k_main  <<<dim3(NGR), dim3(512), 80640, stream>>>(Ah2, x, W1p, b1, W23p, b2, b3,
                                                    eps, Wf1, bf1, dout, hh);
  k_gemm_sig<<<dim3(4, 16), dim3(256), 0, stream>>>(hh, Wf2t, bf2v, dout);
}